// Round 4
// baseline (188.330 us; speedup 1.0000x reference)
//
#include <hip/hip_runtime.h>
#include <stdint.h>

#define NB 16
#define NN 4096
#define KK 10
#define NL 8        // (unsorted path) pass1 groups per wave
#define NL2 11      // (sorted path) per-wave top-11 oct-min list
#define LP2 11      // (sorted path) pass1 list pitch in f32 (odd -> conflict-free)
#define NSEL 11     // tau = 11th-smallest of the 8-wave union
#define LPITCH 9    // (unsorted path) pass1 list pitch in f32
#define FD 64
#define TOTAL (NB * NN)
#define NW 8        // waves per knn block
#define CH 512      // candidates per wave chunk (NW*CH == NN)
#define QG 64       // queries per block (one per lane)
#define WCAP 24     // (unsorted path) survivor cap per (query,wave) cell
#define WPITCH 25   // (unsorted path) cell pitch in halfwords
#define QCAP 192    // (sorted path) per-QUERY survivor cap (mean ~50, big margin)
#define SLOTP 11    // merge-list pitch in u64
#define GSZ 32      // candidates per bbox group
#define NGRP (TOTAL / GSZ)   // 2048 groups

// sorted-path workspace layout (beyond the bucket region)
#define OFF_HIST 18087936
#define OFF_OIDX 18350080
#define OFF_BBX  18481152
#define SORTED_NEED 18546688

#define INFF __int_as_float(0x7f800000)

typedef float f2 __attribute__((ext_vector_type(2)));

// Packed membership distance WITHOUT the +sqi term: t = q - 2*dot.
// sqi is folded into the threshold (guard covers the fold + packed-vs-exact).
// MEMBERSHIP ONLY - final keys use d2exact.
__device__ __forceinline__ f2 FdP3(f2 cx, f2 cy, f2 cz, f2 cq,
                                   f2 vx2, f2 vy2, f2 vz2) {
#pragma clang fp contract(fast)
    f2 t = vx2 * cx + cq;
    t = vy2 * cy + t;
    t = vz2 * cz + t;
    return t;
}

// EXACT numpy rounding - frozen since round 1 (absmax 0.75). DO NOT CHANGE.
__device__ __forceinline__ uint32_t d2exact(float mx, float my, float mz, float sqi,
                                            float cx, float cy, float cz, float cw) {
    float dot = __fadd_rn(__fadd_rn(__fmul_rn(mx, cx), __fmul_rn(my, cy)),
                          __fmul_rn(mz, cz));
    float d2 = __fsub_rn(__fadd_rn(sqi, cw), __fmul_rn(2.0f, dot));
    return __float_as_uint(d2);
}

// 4-bit spread for Morton (b3..b0 -> bits 9,6,3,0)
__device__ __forceinline__ uint32_t sp3(int v) {
    uint32_t x = (uint32_t)v;
    return (x & 1u) | ((x & 2u) << 2) | ((x & 4u) << 4) | ((x & 8u) << 6);
}

__device__ __forceinline__ uint32_t cellcode(float x, float y, float z) {
    int cx = (int)floorf((x + 4.0f) * 2.0f);
    int cy = (int)floorf((y + 4.0f) * 2.0f);
    int cz = (int)floorf((z + 4.0f) * 2.0f);
    cx = cx < 0 ? 0 : (cx > 15 ? 15 : cx);
    cy = cy < 0 ? 0 : (cy > 15 ? 15 : cy);
    cz = cz < 0 ? 0 : (cz > 15 ? 15 : cz);
    return (sp3(cx) << 2) | (sp3(cy) << 1) | sp3(cz);
}

// ---------------------------------------------------------------------------
// Sorted-path prep chain: hist -> scan16 -> scatter -> bbox.
// Sorting is a pure permutation (coords copied bitwise); Morton cells affect
// only ORDER, never correctness.
// ---------------------------------------------------------------------------
__global__ __launch_bounds__(256) void hist_kernel(const float* __restrict__ pos,
                                                   int* __restrict__ hist,
                                                   int* __restrict__ cnt) {
    const int i = blockIdx.x * 256 + threadIdx.x;
    const float* s = pos + (size_t)i * 3;
    float x = s[0], y = s[1], z = s[2];
    uint32_t code = cellcode(x, y, z);
    atomicAdd(&hist[(uint32_t)((i >> 12) << 12) | code], 1);
    cnt[i] = 0;
}

__global__ __launch_bounds__(512) void scan_kernel16(int* __restrict__ hist) {
    __shared__ int lds[512];
    const int t = threadIdx.x;
    int* h = hist + (blockIdx.x << 12);
    const int base = t * 8;
    int v[8];
    int s = 0;
#pragma unroll
    for (int j = 0; j < 8; j++) { v[j] = h[base + j]; s += v[j]; }
    lds[t] = s;
    __syncthreads();
    for (int off = 1; off < 512; off <<= 1) {
        int u = (t >= off) ? lds[t - off] : 0;
        __syncthreads();
        lds[t] += u;
        __syncthreads();
    }
    int run = lds[t] - s;  // exclusive
#pragma unroll
    for (int j = 0; j < 8; j++) { h[base + j] = run; run += v[j]; }
}

__global__ __launch_bounds__(256) void scatter_kernel(const float* __restrict__ pos,
                                                      int* __restrict__ offs,
                                                      float* __restrict__ pp4sf,
                                                      uint16_t* __restrict__ oidx) {
    const int i = blockIdx.x * 256 + threadIdx.x;
    const float* s = pos + (size_t)i * 3;
    float x = s[0], y = s[1], z = s[2];
    float q = __fadd_rn(__fadd_rn(__fmul_rn(x, x), __fmul_rn(y, y)),
                        __fmul_rn(z, z));
    uint32_t code = cellcode(x, y, z);
    int sl = atomicAdd(&offs[(uint32_t)((i >> 12) << 12) | code], 1);
    int gs = ((i >> 12) << 12) | sl;  // global sorted slot
    // pair-packed: floats at 8p: [x0,x1,y0,y1,z0,z1,q0,q1]
    float* dst = pp4sf + (size_t)(gs >> 1) * 8 + (gs & 1);
    dst[0] = x; dst[2] = y; dst[4] = z; dst[6] = q;
    oidx[gs] = (uint16_t)(i & 4095);
}

__global__ __launch_bounds__(256) void bbox_kernel(const float4* __restrict__ pp4s,
                                                   float* __restrict__ bbx) {
    const int grp = blockIdx.x * 8 + (threadIdx.x >> 5);
    const int sub = threadIdx.x & 31;
    const int gs = grp * GSZ + sub;
    float4 A = pp4s[(gs >> 1) * 2 + 0];
    float4 B = pp4s[(gs >> 1) * 2 + 1];
    bool hi = gs & 1;
    float x = hi ? A.y : A.x, y = hi ? A.w : A.z, z = hi ? B.y : B.x;
    float nx = x, xx = x, ny = y, xy = y, nz = z, xz = z;
#pragma unroll
    for (int o = 1; o < 32; o <<= 1) {
        nx = fminf(nx, __shfl_xor(nx, o, 32)); xx = fmaxf(xx, __shfl_xor(xx, o, 32));
        ny = fminf(ny, __shfl_xor(ny, o, 32)); xy = fmaxf(xy, __shfl_xor(xy, o, 32));
        nz = fminf(nz, __shfl_xor(nz, o, 32)); xz = fmaxf(xz, __shfl_xor(xz, o, 32));
    }
    if (sub == 0) {
        float* d = bbx + (size_t)grp * 8;
        d[0] = nx; d[1] = xx; d[2] = ny; d[3] = xy; d[4] = nz; d[5] = xz;
        d[6] = 0.f; d[7] = 0.f;
    }
}

// ---------------------------------------------------------------------------
// SORTED kNN. R2/R3 POST-MORTEM: tau built from group-mins where each wave's
// groups lived inside ONE Morton chunk -> only the ~8 home-chunk groups had
// small mins -> 11th-smallest jumped to a FAR region -> tau huge -> pool
// overflow -> silent drops -> wrong. Fix: pass1 samples CROSS-BATCH pairs
// p = w + 16j + 512m (each oct = 4 pairs spread 512 pairs apart; the wave id
// cycles with p mod 8, so a contiguous near-run spreads over ~30+ distinct
// octs of the union). Per-wave top-11 oct-min list (NL2=11, med3 insert) +
// 8-list merge -> tau at candidate-rank ~40-60. Validity is correlation-free:
// tau = 11th-smallest oct-min => >=11 distinct cands with e <= tau; pass2
// (contiguous chunks + bbox skip, skip provably keeps all e<=tau members)
// pushes them all; >=10 non-self => exact top-10. Rescore key tiebreak uses
// ORIGINAL index so d2-ties order exactly as the reference.
// ---------------------------------------------------------------------------
__global__ __launch_bounds__(512, 8) void knn_sorted_kernel(
        const float4* __restrict__ pp4,
        const uint16_t* __restrict__ oidx,
        const float* __restrict__ bbx,
        int* __restrict__ cnt,
        int* __restrict__ colfix,
        int* __restrict__ nbr) {
    // 25.6 KB region, time-multiplexed:
    //   phase A: pass1 lists   512*11 f32    = 22.5 KB
    //   phase B: survivor pool 64*192 u16    = 24.6 KB (per-query lists)
    //   phase C: merge slots   4*64*11 u64   = 22.5 KB
    __shared__ uint64_t smem8[3200];
    __shared__ float tau_s[QG];
    __shared__ uint32_t qcnt[QG];
    float* listf = (float*)smem8;
    uint16_t* pool16 = (uint16_t*)smem8;
    uint64_t* slot = smem8;

    const int tid = threadIdx.x;
    const int lane = tid & 63;
    const int w = __builtin_amdgcn_readfirstlane(tid >> 6);
    const int batch = blockIdx.x & 15;                  // XCD-affinity swizzle
    const int qs = ((blockIdx.x >> 4) << 6) | lane;     // SORTED batch-local query
    const int gbase = batch << 12;
    const int gqs = gbase + qs;

    float4 mA = pp4[(gqs >> 1) * 2 + 0];
    float4 mB = pp4[(gqs >> 1) * 2 + 1];
    const bool hi = (qs & 1);
    const float mx = hi ? mA.y : mA.x;
    const float my = hi ? mA.w : mA.z;
    const float mz = hi ? mB.y : mB.x;
    const float sqi = hi ? mB.w : mB.z;
    const f2 vx22 = {__fmul_rn(-2.0f, mx), __fmul_rn(-2.0f, mx)};
    const f2 vy22 = {__fmul_rn(-2.0f, my), __fmul_rn(-2.0f, my)};
    const f2 vz22 = {__fmul_rn(-2.0f, mz), __fmul_rn(-2.0f, mz)};

    const f2* __restrict__ bp2 = (const f2*)(pp4 + (size_t)gbase);   // batch base
    const f2* __restrict__ cp2 = (const f2*)(pp4 + (size_t)(gbase + w * CH));

#define D8P(cb2)                                                      \
    f2 X0 = (cb2)[0],  Y0 = (cb2)[1],  Z0 = (cb2)[2],  Q0 = (cb2)[3]; \
    f2 X1 = (cb2)[4],  Y1 = (cb2)[5],  Z1 = (cb2)[6],  Q1 = (cb2)[7]; \
    f2 X2 = (cb2)[8],  Y2 = (cb2)[9],  Z2 = (cb2)[10], Q2 = (cb2)[11];\
    f2 X3 = (cb2)[12], Y3 = (cb2)[13], Z3 = (cb2)[14], Q3 = (cb2)[15];\
    f2 e0 = FdP3(X0, Y0, Z0, Q0, vx22, vy22, vz22);                   \
    f2 e1 = FdP3(X1, Y1, Z1, Q1, vx22, vy22, vz22);                   \
    f2 e2 = FdP3(X2, Y2, Z2, Q2, vx22, vy22, vz22);                   \
    f2 e3 = FdP3(X3, Y3, Z3, Q3, vx22, vy22, vz22);

    // ---- pass 1: 32 CROSS-BATCH oct-mins per wave -> top-11 list.
    // Oct j = pairs {w + 16j + 512m : m=0..3} (4 pairs, 512 pairs apart).
    float L[NL2];
#pragma unroll
    for (int t = 0; t < NL2; t++) L[t] = INFF;

#pragma unroll 2
    for (int j = 0; j < 32; ++j) {
        float m = INFF;
#pragma unroll
        for (int s = 0; s < 4; ++s) {
            const f2* c2 = bp2 + (((s << 9) | (j << 4) | w) << 2);  // pair idx *4
            f2 X = c2[0], Y = c2[1], Z = c2[2], Q = c2[3];
            f2 e = FdP3(X, Y, Z, Q, vx22, vy22, vz22);
            m = fminf(m, fminf(e.x, e.y));
        }
        // sorted-descending insert (L[NL2-1] = smallest)
#pragma unroll
        for (int t = 0; t < NL2 - 1; ++t) L[t] = __builtin_amdgcn_fmed3f(L[t], L[t + 1], m);
        L[NL2 - 1] = fminf(L[NL2 - 1], m);
    }
#pragma unroll
    for (int t = 0; t < NL2; t++) listf[tid * LP2 + t] = L[t];
    __syncthreads();

    // ---- merge: 11th-smallest oct-min of the 8-list union -> tau
    if (tid < QG) {
        int p[NW];
#pragma unroll
        for (int u = 0; u < NW; u++) p[u] = NL2 - 1;  // descending; tail = min
        float tau = INFF;
        for (int it = 0; it < NSEL; ++it) {
            float best = INFF;
            int bw = 0;
#pragma unroll
            for (int u = 0; u < NW; u++) {
                float v = (p[u] >= 0) ? listf[((u << 6) | tid) * LP2 + p[u]] : INFF;
                if (v < best) { best = v; bw = u; }
            }
            p[bw]--;
            tau = best;
        }
        tau_s[tid] = tau;
        qcnt[tid] = 0;
    }
    __syncthreads();  // merge reads done; pool16 may now overwrite list region

    // ---- pass 2: bbox group-skip + packed replay into per-query list
    const float t0v = tau_s[lane];
    const float tau = t0v + fabsf(t0v) * 1e-4f + 1e-4f;
    const float taud2 = __fadd_rn(tau, sqi) + 1e-4f;  // true-d2-space bound
#pragma unroll 1
    for (int og = 0; og < 16; ++og) {
        const float* bb = bbx + (size_t)((batch << 7) | (w << 4) | og) * 8;
        float dx = fmaxf(fmaxf(bb[0] - mx, mx - bb[1]), 0.0f);
        float dy = fmaxf(fmaxf(bb[2] - my, my - bb[3]), 0.0f);
        float dz = fmaxf(fmaxf(bb[4] - mz, mz - bb[5]), 0.0f);
        float d2lb = dx * dx + dy * dy + dz * dz;
        if (__any(d2lb <= taud2)) {
#pragma unroll
            for (int s = 0; s < 4; ++s) {
                const f2* cb2 = cp2 + (og * 4 + s) * 16;
                D8P(cb2);
                const uint32_t jb = (uint32_t)(w * CH + (og * 4 + s) * 8);
                bool h0 = e0.x <= tau, h1 = e0.y <= tau, h2 = e1.x <= tau, h3 = e1.y <= tau;
                bool h4 = e2.x <= tau, h5 = e2.y <= tau, h6 = e3.x <= tau, h7 = e3.y <= tau;
#define PUSH(hv, off)                                                   \
                if (hv) {                                               \
                    uint32_t p = atomicAdd(&qcnt[lane], 1u);            \
                    if (p < QCAP) pool16[lane * QCAP + p] = (uint16_t)(jb + (off)); \
                }
                if (h0 | h1) { PUSH(h0, 0) PUSH(h1, 1) }
                if (h2 | h3) { PUSH(h2, 2) PUSH(h3, 3) }
                if (h4 | h5) { PUSH(h4, 4) PUSH(h5, 5) }
                if (h6 | h7) { PUSH(h6, 6) PUSH(h7, 7) }
#undef PUSH
            }
        }
    }
    __syncthreads();  // all pushes visible (lists are cross-wave now)

    // ---- rescore: wave w takes entries w, w+8, ... of its lane-query's list.
    // Key = (d2exact << 32) | ORIGINAL idx -> tie order matches reference.
    uint64_t S[KK];
#pragma unroll
    for (int t = 0; t < KK; t++) S[t] = ~0ull;
    {
        uint32_t len = qcnt[lane];
        if (len > QCAP) len = QCAP;
        const uint16_t* st = pool16 + lane * QCAP;
        for (uint32_t e = (uint32_t)w; e < len; e += NW) {
            uint32_t ix = st[e];
            if (ix == (uint32_t)qs) continue;  // self (sorted id)
            int g = gbase + (int)ix;
            float4 A4 = pp4[(g >> 1) * 2 + 0];
            float4 B4 = pp4[(g >> 1) * 2 + 1];
            bool ch = (ix & 1);
            uint32_t db = d2exact(mx, my, mz, sqi,
                                  ch ? A4.y : A4.x, ch ? A4.w : A4.z,
                                  ch ? B4.y : B4.x, ch ? B4.w : B4.z);
            uint32_t orig = (uint32_t)oidx[g];
            uint64_t k64 = ((uint64_t)db << 32) | orig;
            if (k64 < S[0]) {
                bool sh[KK];
                sh[0] = true;
#pragma unroll
                for (int t = 1; t < KK; t++) sh[t] = (k64 < S[t]);
#pragma unroll
                for (int t = 0; t < KK; t++) {
                    uint64_t vac = sh[t] ? k64 : S[t];
                    S[t] = (t + 1 < KK) ? (sh[t + 1] ? S[t + 1] : vac) : vac;
                }
            }
        }
    }
    __syncthreads();  // all pool reads done; slots may overwrite pool region

    // ---- merge tree: rank-scatter ('<' A side, '<=' B side -> bijective)
    if (w >= 4) {
        uint64_t* sl = slot + (((w - 4) << 6) | lane) * SLOTP;
#pragma unroll
        for (int j = 0; j < KK; ++j) sl[j] = S[KK - 1 - j];  // ascending
    }
    __syncthreads();

    if (w < 4) {
        uint64_t* sl = slot + ((w << 6) | lane) * SLOTP;
        uint64_t P[KK];
#pragma unroll
        for (int j = 0; j < KK; ++j) P[j] = sl[j];
#pragma unroll
        for (int j = 0; j < KK; ++j) {
            uint64_t v = S[KK - 1 - j];
            uint32_t r = (uint32_t)j;
#pragma unroll
            for (int i = 0; i < KK; ++i) r += (P[i] < v) ? 1u : 0u;
            if (r < KK) sl[r] = v;
        }
#pragma unroll
        for (int i = 0; i < KK; ++i) {
            uint64_t v = P[i];
            uint32_t r = (uint32_t)i;
#pragma unroll
            for (int t = 0; t < KK; ++t) r += (S[t] <= v) ? 1u : 0u;
            if (r < KK) sl[r] = v;
        }
    }
    __syncthreads();

    if (w < 2) {
        uint64_t* sa = slot + (((w * 2) << 6) | lane) * SLOTP;
        uint64_t* sb = slot + (((w * 2 + 1) << 6) | lane) * SLOTP;
        uint64_t Aa[KK], Bb[KK];
#pragma unroll
        for (int j = 0; j < KK; ++j) Aa[j] = sa[j];
#pragma unroll
        for (int j = 0; j < KK; ++j) Bb[j] = sb[j];
#pragma unroll
        for (int j = 0; j < KK; ++j) {
            uint32_t r = (uint32_t)j;
#pragma unroll
            for (int i = 0; i < KK; ++i) r += (Bb[i] < Aa[j]) ? 1u : 0u;
            if (r < KK) sa[r] = Aa[j];
        }
#pragma unroll
        for (int i = 0; i < KK; ++i) {
            uint32_t r = (uint32_t)i;
#pragma unroll
            for (int j = 0; j < KK; ++j) r += (Aa[j] <= Bb[i]) ? 1u : 0u;
            if (r < KK) sa[r] = Bb[i];
        }
    }
    __syncthreads();

    if (tid < QG) {
        const uint64_t* sa = slot + ((0 << 6) | tid) * SLOTP;
        const uint64_t* sb = slot + ((2 << 6) | tid) * SLOTP;
        uint64_t Aa[KK], Bb[KK];
#pragma unroll
        for (int j = 0; j < KK; ++j) Aa[j] = sa[j];
#pragma unroll
        for (int j = 0; j < KK; ++j) Bb[j] = sb[j];
        const int gq_o = gbase + (int)oidx[gbase + qs];  // orig query id
        // sentinel guard: with valid tau this never triggers; it prevents
        // memory corruption if an assumption ever breaks.
#define EMIT(key, rk)                                              \
        if ((uint32_t)((key) >> 32) != 0xffffffffu) {              \
            int jl = (int)((key) & 0xffffffffu);                   \
            int gj = gbase + jl;   /* key already holds ORIG idx */\
            int p = atomicAdd(&cnt[gj], 1);                        \
            if (colfix) {                                          \
                if (p < 64) colfix[(gj << 6) | p] = gq_o;          \
            } else {                                               \
                nbr[gq_o * KK + (int)(rk)] = gj;                   \
            }                                                      \
        }
#pragma unroll
        for (int j = 0; j < KK; ++j) {
            uint32_t r = (uint32_t)j;
#pragma unroll
            for (int i = 0; i < KK; ++i) r += (Bb[i] < Aa[j]) ? 1u : 0u;
            if (r < KK) EMIT(Aa[j], r)
        }
#pragma unroll
        for (int i = 0; i < KK; ++i) {
            uint32_t r = (uint32_t)i;
#pragma unroll
            for (int j = 0; j < KK; ++j) r += (Aa[j] <= Bb[i]) ? 1u : 0u;
            if (r < KK) EMIT(Bb[i], r)
        }
#undef EMIT
    }
#undef D8P
}

// ---------------------------------------------------------------------------
// UNSORTED prep + kNN (round-1 verbatim) - fallback when ws lacks sort space.
// ---------------------------------------------------------------------------
__global__ __launch_bounds__(256) void prep_kernel(const float* __restrict__ pos,
                                                   float4* __restrict__ pp4,
                                                   int* __restrict__ cnt) {
    const int p = blockIdx.x * 256 + threadIdx.x;
    const float* s = pos + (size_t)p * 6;
    float x0 = s[0], y0 = s[1], z0 = s[2];
    float x1 = s[3], y1 = s[4], z1 = s[5];
    float q0 = __fadd_rn(__fadd_rn(__fmul_rn(x0, x0), __fmul_rn(y0, y0)),
                         __fmul_rn(z0, z0));
    float q1 = __fadd_rn(__fadd_rn(__fmul_rn(x1, x1), __fmul_rn(y1, y1)),
                         __fmul_rn(z1, z1));
    pp4[2 * p + 0] = make_float4(x0, x1, y0, y1);
    pp4[2 * p + 1] = make_float4(z0, z1, q0, q1);
    cnt[2 * p + 0] = 0;
    cnt[2 * p + 1] = 0;
}

__global__ __launch_bounds__(512, 8) void knn_kernel(const float4* __restrict__ pp4,
                                                     int* __restrict__ cnt,
                                                     int* __restrict__ colfix,
                                                     int* __restrict__ nbr) {
    __shared__ uint64_t smem8[3200];
    __shared__ float tau_s[QG];
    float* listf = (float*)smem8;
    uint16_t* pool16 = (uint16_t*)smem8;
    uint64_t* slot = smem8;

    const int tid = threadIdx.x;
    const int lane = tid & 63;
    const int w = __builtin_amdgcn_readfirstlane(tid >> 6);
    const int batch = blockIdx.x & 15;
    const int qloc = ((blockIdx.x >> 4) << 6) | lane;
    const int gbase = batch << 12;
    const int gq = gbase + qloc;

    float4 mA = pp4[(gq >> 1) * 2 + 0];
    float4 mB = pp4[(gq >> 1) * 2 + 1];
    const bool hi = (qloc & 1);
    const float mx = hi ? mA.y : mA.x;
    const float my = hi ? mA.w : mA.z;
    const float mz = hi ? mB.y : mB.x;
    const float sqi = hi ? mB.w : mB.z;
    const f2 vx22 = {__fmul_rn(-2.0f, mx), __fmul_rn(-2.0f, mx)};
    const f2 vy22 = {__fmul_rn(-2.0f, my), __fmul_rn(-2.0f, my)};
    const f2 vz22 = {__fmul_rn(-2.0f, mz), __fmul_rn(-2.0f, mz)};

    const f2* __restrict__ cp2 = (const f2*)(pp4 + (size_t)(gbase + w * CH));

#define D8P(cb2)                                                      \
    f2 X0 = (cb2)[0],  Y0 = (cb2)[1],  Z0 = (cb2)[2],  Q0 = (cb2)[3]; \
    f2 X1 = (cb2)[4],  Y1 = (cb2)[5],  Z1 = (cb2)[6],  Q1 = (cb2)[7]; \
    f2 X2 = (cb2)[8],  Y2 = (cb2)[9],  Z2 = (cb2)[10], Q2 = (cb2)[11];\
    f2 X3 = (cb2)[12], Y3 = (cb2)[13], Z3 = (cb2)[14], Q3 = (cb2)[15];\
    f2 e0 = FdP3(X0, Y0, Z0, Q0, vx22, vy22, vz22);                   \
    f2 e1 = FdP3(X1, Y1, Z1, Q1, vx22, vy22, vz22);                   \
    f2 e2 = FdP3(X2, Y2, Z2, Q2, vx22, vy22, vz22);                   \
    f2 e3 = FdP3(X3, Y3, Z3, Q3, vx22, vy22, vz22);

    float L[NL];
#pragma unroll
    for (int t = 0; t < NL; t++) L[t] = INFF;

#pragma unroll 2
    for (int g = 0; g < NL; ++g) {
        float gm = INFF;
#pragma unroll
        for (int s = 0; s < 4; ++s) {
            const f2* cb2 = cp2 + (g * 4 + s) * 16;
            D8P(cb2);
            float m = fminf(fminf(fminf(e0.x, e0.y), fminf(e1.x, e1.y)),
                            fminf(fminf(e2.x, e2.y), fminf(e3.x, e3.y)));
            gm = fminf(gm, m);
        }
#pragma unroll
        for (int t = 0; t < NL - 1; ++t) L[t] = __builtin_amdgcn_fmed3f(L[t], L[t + 1], gm);
        L[NL - 1] = fminf(L[NL - 1], gm);
    }
#pragma unroll
    for (int t = 0; t < NL; t++) listf[tid * LPITCH + t] = L[t];
    __syncthreads();

    if (tid < QG) {
        int p[NW];
#pragma unroll
        for (int u = 0; u < NW; u++) p[u] = NL - 1;
        float tau = INFF;
        for (int it = 0; it < NSEL; ++it) {
            float best = INFF;
            int bw = 0;
#pragma unroll
            for (int u = 0; u < NW; u++) {
                float v = (p[u] >= 0) ? listf[((u << 6) | tid) * LPITCH + p[u]] : INFF;
                if (v < best) { best = v; bw = u; }
            }
            p[bw]--;
            tau = best;
        }
        tau_s[tid] = tau;
    }
    __syncthreads();

    const float t0v = tau_s[lane];
    const float tau = t0v + fabsf(t0v) * 1e-4f + 1e-4f;
    const uint32_t cell0 = (uint32_t)(((w << 6) | lane) * WPITCH);
    uint32_t cpos = cell0;
#pragma unroll 2
    for (int o = 0; o < CH / 8; ++o) {
        const f2* cb2 = cp2 + o * 16;
        D8P(cb2);
        const uint32_t jb = (uint32_t)(w * CH + o * 8);
        bool h0 = e0.x <= tau, h1 = e0.y <= tau, h2 = e1.x <= tau, h3 = e1.y <= tau;
        bool h4 = e2.x <= tau, h5 = e2.y <= tau, h6 = e3.x <= tau, h7 = e3.y <= tau;
#define PUSH(hv, off)                                              \
        if ((hv) && cpos < cell0 + WCAP) {                         \
            pool16[cpos] = (uint16_t)(jb + (off));                 \
            cpos++;                                                \
        }
        if (h0 | h1) { PUSH(h0, 0) PUSH(h1, 1) }
        if (h2 | h3) { PUSH(h2, 2) PUSH(h3, 3) }
        if (h4 | h5) { PUSH(h4, 4) PUSH(h5, 5) }
        if (h6 | h7) { PUSH(h6, 6) PUSH(h7, 7) }
#undef PUSH
    }

    uint64_t S[KK];
#pragma unroll
    for (int t = 0; t < KK; t++) S[t] = ~0ull;
    {
        const uint16_t* st = pool16 + cell0;
        const int c2i = (int)(cpos - cell0);
        for (int e = 0; e < c2i; ++e) {
            uint32_t ix = st[e];
            if (ix == (uint32_t)qloc) continue;
            int g = gbase + (int)ix;
            float4 A4 = pp4[(g >> 1) * 2 + 0];
            float4 B4 = pp4[(g >> 1) * 2 + 1];
            bool ch = (ix & 1);
            uint32_t db = d2exact(mx, my, mz, sqi,
                                  ch ? A4.y : A4.x, ch ? A4.w : A4.z,
                                  ch ? B4.y : B4.x, ch ? B4.w : B4.z);
            uint64_t k64 = ((uint64_t)db << 32) | ix;
            if (k64 < S[0]) {
                bool sh[KK];
                sh[0] = true;
#pragma unroll
                for (int t = 1; t < KK; t++) sh[t] = (k64 < S[t]);
#pragma unroll
                for (int t = 0; t < KK; t++) {
                    uint64_t vac = sh[t] ? k64 : S[t];
                    S[t] = (t + 1 < KK) ? (sh[t + 1] ? S[t + 1] : vac) : vac;
                }
            }
        }
    }
    __syncthreads();

    if (w >= 4) {
        uint64_t* sl = slot + (((w - 4) << 6) | lane) * SLOTP;
#pragma unroll
        for (int j = 0; j < KK; ++j) sl[j] = S[KK - 1 - j];
    }
    __syncthreads();

    if (w < 4) {
        uint64_t* sl = slot + ((w << 6) | lane) * SLOTP;
        uint64_t P[KK];
#pragma unroll
        for (int j = 0; j < KK; ++j) P[j] = sl[j];
#pragma unroll
        for (int j = 0; j < KK; ++j) {
            uint64_t v = S[KK - 1 - j];
            uint32_t r = (uint32_t)j;
#pragma unroll
            for (int i = 0; i < KK; ++i) r += (P[i] < v) ? 1u : 0u;
            if (r < KK) sl[r] = v;
        }
#pragma unroll
        for (int i = 0; i < KK; ++i) {
            uint64_t v = P[i];
            uint32_t r = (uint32_t)i;
#pragma unroll
            for (int t = 0; t < KK; ++t) r += (S[t] <= v) ? 1u : 0u;
            if (r < KK) sl[r] = v;
        }
    }
    __syncthreads();

    if (w < 2) {
        uint64_t* sa = slot + (((w * 2) << 6) | lane) * SLOTP;
        uint64_t* sb = slot + (((w * 2 + 1) << 6) | lane) * SLOTP;
        uint64_t Aa[KK], Bb[KK];
#pragma unroll
        for (int j = 0; j < KK; ++j) Aa[j] = sa[j];
#pragma unroll
        for (int j = 0; j < KK; ++j) Bb[j] = sb[j];
#pragma unroll
        for (int j = 0; j < KK; ++j) {
            uint32_t r = (uint32_t)j;
#pragma unroll
            for (int i = 0; i < KK; ++i) r += (Bb[i] < Aa[j]) ? 1u : 0u;
            if (r < KK) sa[r] = Aa[j];
        }
#pragma unroll
        for (int i = 0; i < KK; ++i) {
            uint32_t r = (uint32_t)i;
#pragma unroll
            for (int j = 0; j < KK; ++j) r += (Aa[j] <= Bb[i]) ? 1u : 0u;
            if (r < KK) sa[r] = Bb[i];
        }
    }
    __syncthreads();

    if (tid < QG) {
        const uint64_t* sa = slot + ((0 << 6) | tid) * SLOTP;
        const uint64_t* sb = slot + ((2 << 6) | tid) * SLOTP;
        uint64_t Aa[KK], Bb[KK];
#pragma unroll
        for (int j = 0; j < KK; ++j) Aa[j] = sa[j];
#pragma unroll
        for (int j = 0; j < KK; ++j) Bb[j] = sb[j];
#define EMIT(key, rk)                                              \
        {                                                          \
            int jl = (int)((key) & 0xffffffffu);                   \
            int gj = gbase + jl;                                   \
            int p = atomicAdd(&cnt[gj], 1);                        \
            if (colfix) {                                          \
                if (p < 64) colfix[(gj << 6) | p] = gq;            \
            } else {                                               \
                nbr[gq * KK + (int)(rk)] = gj;                     \
            }                                                      \
        }
#pragma unroll
        for (int j = 0; j < KK; ++j) {
            uint32_t r = (uint32_t)j;
#pragma unroll
            for (int i = 0; i < KK; ++i) r += (Bb[i] < Aa[j]) ? 1u : 0u;
            if (r < KK) EMIT(Aa[j], r)
        }
#pragma unroll
        for (int i = 0; i < KK; ++i) {
            uint32_t r = (uint32_t)i;
#pragma unroll
            for (int j = 0; j < KK; ++j) r += (Aa[j] <= Bb[i]) ? 1u : 0u;
            if (r < KK) EMIT(Bb[i], r)
        }
#undef EMIT
    }
#undef D8P
}

// ---------------------------------------------------------------------------
// Bucket-path output (unchanged).
// ---------------------------------------------------------------------------
__global__ __launch_bounds__(256) void out_bucket_kernel(const float4* __restrict__ x4,
                                                         const int* __restrict__ colfix,
                                                         const int* __restrict__ cnt,
                                                         float* __restrict__ out) {
    const int b = blockIdx.x;
    const int g = b & 15;
    const int i = b >> 4;
    const int l = threadIdx.x & 31;
    const int n = (g << 12) | (i << 3) | (threadIdx.x >> 5);
    const int s = l & 15;
    const int half = l >> 4;
    const int c = cnt[n];
    const int cc = (c > 64) ? 64 : c;
    const int4* cf4 = (const int4*)(colfix + ((size_t)n << 6));
    float4 acc = make_float4(0.f, 0.f, 0.f, 0.f);
    for (int eb = half * 4; eb < cc; eb += 8) {
        int4 Q = cf4[eb >> 2];
        float4 v0 = x4[((size_t)Q.x << 4) | s];
        acc.x += v0.x; acc.y += v0.y; acc.z += v0.z; acc.w += v0.w;
        if (eb + 1 < cc) {
            float4 v1 = x4[((size_t)Q.y << 4) | s];
            acc.x += v1.x; acc.y += v1.y; acc.z += v1.z; acc.w += v1.w;
        }
        if (eb + 2 < cc) {
            float4 v2 = x4[((size_t)Q.z << 4) | s];
            acc.x += v2.x; acc.y += v2.y; acc.z += v2.z; acc.w += v2.w;
        }
        if (eb + 3 < cc) {
            float4 v3 = x4[((size_t)Q.w << 4) | s];
            acc.x += v3.x; acc.y += v3.y; acc.z += v3.z; acc.w += v3.w;
        }
    }
    acc.x += __shfl_xor(acc.x, 16, 64);
    acc.y += __shfl_xor(acc.y, 16, 64);
    acc.z += __shfl_xor(acc.z, 16, 64);
    acc.w += __shfl_xor(acc.w, 16, 64);
    const float inv = 1.0f / (float)(c > 1 ? c : 1);
    float4 mn = x4[((size_t)n << 4) | s];
    float v = fabsf(mn.x - acc.x * inv) + fabsf(mn.y - acc.y * inv) +
              fabsf(mn.z - acc.z * inv) + fabsf(mn.w - acc.w * inv);
    v += __shfl_xor(v, 1, 64);
    v += __shfl_xor(v, 2, 64);
    v += __shfl_xor(v, 4, 64);
    v += __shfl_xor(v, 8, 64);
    if (l == 0) out[n] = v;
}

// ------------------------- fallback path (small ws) -------------------------
__global__ __launch_bounds__(1024) void scan_kernel(const int* __restrict__ cnt,
                                                    int* __restrict__ offs) {
    __shared__ int lds[1024];
    const int t = threadIdx.x;
    const int base = t * 64;
    int s = 0;
    for (int i = 0; i < 64; i++) s += cnt[base + i];
    lds[t] = s;
    __syncthreads();
    for (int off = 1; off < 1024; off <<= 1) {
        int v = (t >= off) ? lds[t - off] : 0;
        __syncthreads();
        lds[t] += v;
        __syncthreads();
    }
    int run = lds[t] - s;
    for (int i = 0; i < 64; i++) {
        offs[base + i] = run;
        run += cnt[base + i];
    }
}

__global__ __launch_bounds__(256) void fill_kernel(const int* __restrict__ nbr,
                                                   int* __restrict__ offs,
                                                   int* __restrict__ col) {
    const int i = blockIdx.x * 256 + threadIdx.x;
#pragma unroll
    for (int t = 0; t < KK; t++) {
        int j = nbr[i * KK + t];
        int p = atomicAdd(&offs[j], 1);
        col[p] = i;
    }
}

__global__ __launch_bounds__(256) void out_kernel(const float* __restrict__ x,
                                                  const int* __restrict__ col,
                                                  const int* __restrict__ offs_end,
                                                  const int* __restrict__ cnt,
                                                  float* __restrict__ out) {
    const int gtid = blockIdx.x * 256 + threadIdx.x;
    const int n = gtid >> 6;
    const int lane = gtid & 63;
    const int c = cnt[n];
    const int end = offs_end[n];
    const int start = end - c;
    float s = 0.0f;
    for (int e = start; e < end; e++) {
        int i = col[e];
        s += x[(size_t)i * FD + lane];
    }
    float mean = s / (float)(c > 1 ? c : 1);
    float v = fabsf(x[(size_t)n * FD + lane] - mean);
#pragma unroll
    for (int off = 32; off; off >>= 1) v += __shfl_xor(v, off, 64);
    if (lane == 0) out[n] = v;
}

extern "C" void kernel_launch(void* const* d_in, const int* in_sizes, int n_in,
                              void* d_out, int out_size, void* d_ws, size_t ws_size,
                              hipStream_t stream) {
    const float* x = (const float*)d_in[0];
    const float* pos = (const float*)d_in[1];
    float* out = (float*)d_out;

    char* ws = (char*)d_ws;
    float4* pp4 = (float4*)(ws + 0);            // 1,048,576 B (sorted or unsorted)
    int* cnt = (int*)(ws + 1048576);            //   262,144 B
    int* colfix = (int*)(ws + 1310720);         // 16,777,216 B (bucket path)
    int* nbr = (int*)(ws + 1310720);            //  2,621,440 B (fallback path)
    int* offs = (int*)(ws + 3932160);
    int* col = (int*)(ws + 4194304);
    // sorted-path extras (past colfix):
    int* hist = (int*)(ws + OFF_HIST);          //   262,144 B (bins, then offsets)
    uint16_t* oidx = (uint16_t*)(ws + OFF_OIDX);//   131,072 B (sorted -> orig)
    float* bbx = (float*)(ws + OFF_BBX);        //    65,536 B (group bboxes)

    const bool bucket = ws_size >= (size_t)(1310720 + TOTAL * 64 * 4);
    const bool sorted = ws_size >= (size_t)SORTED_NEED;  // implies bucket

    if (sorted) {
        hipMemsetAsync(hist, 0, NB * 4096 * sizeof(int), stream);
        hipLaunchKernelGGL(hist_kernel, dim3(TOTAL / 256), dim3(256), 0, stream,
                           pos, hist, cnt);
        hipLaunchKernelGGL(scan_kernel16, dim3(NB), dim3(512), 0, stream, hist);
        hipLaunchKernelGGL(scatter_kernel, dim3(TOTAL / 256), dim3(256), 0, stream,
                           pos, hist, (float*)pp4, oidx);
        hipLaunchKernelGGL(bbox_kernel, dim3(NGRP / 8), dim3(256), 0, stream,
                           pp4, bbx);
        hipLaunchKernelGGL(knn_sorted_kernel, dim3(TOTAL / QG), dim3(512), 0, stream,
                           pp4, oidx, bbx, cnt, colfix, (int*)nullptr);
        hipLaunchKernelGGL(out_bucket_kernel, dim3(TOTAL * 32 / 256), dim3(256), 0, stream,
                           (const float4*)x, colfix, cnt, out);
    } else {
        hipLaunchKernelGGL(prep_kernel, dim3(TOTAL / 2 / 256), dim3(256), 0, stream,
                           pos, pp4, cnt);
        hipLaunchKernelGGL(knn_kernel, dim3(TOTAL / QG), dim3(512), 0, stream, pp4, cnt,
                           bucket ? colfix : (int*)nullptr, bucket ? (int*)nullptr : nbr);
        if (bucket) {
            hipLaunchKernelGGL(out_bucket_kernel, dim3(TOTAL * 32 / 256), dim3(256), 0, stream,
                               (const float4*)x, colfix, cnt, out);
        } else {
            hipLaunchKernelGGL(scan_kernel, dim3(1), dim3(1024), 0, stream, cnt, offs);
            hipLaunchKernelGGL(fill_kernel, dim3(TOTAL / 256), dim3(256), 0, stream, nbr, offs, col);
            hipLaunchKernelGGL(out_kernel, dim3(TOTAL * FD / 256), dim3(256), 0, stream,
                               x, col, offs, cnt, out);
        }
    }
}

// Round 7
// 186.624 us; speedup vs baseline: 1.0091x; 1.0091x over previous
//
#include <hip/hip_runtime.h>
#include <stdint.h>

#define NB 16
#define NN 4096
#define KK 10
#define NL 8        // (unsorted path) pass1 groups per wave
#define NL2 11      // (sorted path) per-wave top-11 oct-min list
#define LP2 11      // (sorted path) pass1 list pitch in f32 (odd -> conflict-free)
#define NSEL 11     // tau = 11th-smallest of the 8-wave union
#define LPITCH 9    // (unsorted path) pass1 list pitch in f32
#define FD 64
#define TOTAL (NB * NN)
#define NW 8        // waves per knn block
#define CH 512      // candidates per wave chunk (NW*CH == NN)
#define QG 64       // queries per block (one per lane)
#define WCAP 24     // (unsorted path) survivor cap per (query,wave) cell
#define WPITCH 25   // (unsorted path) cell pitch in halfwords
#define QCAP 192    // (sorted path) per-QUERY survivor cap (mean ~44, P(ovf)~1e-12)
#define QPITCH 198  // R7: pool PITCH in u16. 99 words/lane, gcd(99,32)=1 ->
                    // conflict-free. R4's pitch=QCAP=192 (96 words = 0 mod 32)
                    // made every pool push/read a full-wave bank conflict
                    // (SQ_LDS_BANK_CONFLICT 2.77M). ONLY change vs R4-green.
#define SLOTP 11    // merge-list pitch in u64
#define GSZ 32      // candidates per bbox group
#define NGRP (TOTAL / GSZ)   // 2048 groups

// sorted-path workspace layout (beyond the bucket region)
#define OFF_HIST 18087936
#define OFF_OIDX 18350080
#define OFF_BBX  18481152
#define SORTED_NEED 18546688

#define INFF __int_as_float(0x7f800000)

typedef float f2 __attribute__((ext_vector_type(2)));

// Packed membership distance WITHOUT the +sqi term: t = q - 2*dot.
// sqi is folded into the threshold (guard covers the fold + packed-vs-exact).
// MEMBERSHIP ONLY - final keys use d2exact.
__device__ __forceinline__ f2 FdP3(f2 cx, f2 cy, f2 cz, f2 cq,
                                   f2 vx2, f2 vy2, f2 vz2) {
#pragma clang fp contract(fast)
    f2 t = vx2 * cx + cq;
    t = vy2 * cy + t;
    t = vz2 * cz + t;
    return t;
}

// EXACT numpy rounding - frozen since round 1 (absmax 0.75). DO NOT CHANGE.
__device__ __forceinline__ uint32_t d2exact(float mx, float my, float mz, float sqi,
                                            float cx, float cy, float cz, float cw) {
    float dot = __fadd_rn(__fadd_rn(__fmul_rn(mx, cx), __fmul_rn(my, cy)),
                          __fmul_rn(mz, cz));
    float d2 = __fsub_rn(__fadd_rn(sqi, cw), __fmul_rn(2.0f, dot));
    return __float_as_uint(d2);
}

// 4-bit spread for Morton (b3..b0 -> bits 9,6,3,0)
__device__ __forceinline__ uint32_t sp3(int v) {
    uint32_t x = (uint32_t)v;
    return (x & 1u) | ((x & 2u) << 2) | ((x & 4u) << 4) | ((x & 8u) << 6);
}

__device__ __forceinline__ uint32_t cellcode(float x, float y, float z) {
    int cx = (int)floorf((x + 4.0f) * 2.0f);
    int cy = (int)floorf((y + 4.0f) * 2.0f);
    int cz = (int)floorf((z + 4.0f) * 2.0f);
    cx = cx < 0 ? 0 : (cx > 15 ? 15 : cx);
    cy = cy < 0 ? 0 : (cy > 15 ? 15 : cy);
    cz = cz < 0 ? 0 : (cz > 15 ? 15 : cz);
    return (sp3(cx) << 2) | (sp3(cy) << 1) | sp3(cz);
}

// ---------------------------------------------------------------------------
// Sorted-path prep chain: hist -> scan16 -> scatter -> bbox.
// Sorting is a pure permutation (coords copied bitwise); Morton cells affect
// only ORDER, never correctness.
// ---------------------------------------------------------------------------
__global__ __launch_bounds__(256) void hist_kernel(const float* __restrict__ pos,
                                                   int* __restrict__ hist,
                                                   int* __restrict__ cnt) {
    const int i = blockIdx.x * 256 + threadIdx.x;
    const float* s = pos + (size_t)i * 3;
    float x = s[0], y = s[1], z = s[2];
    uint32_t code = cellcode(x, y, z);
    atomicAdd(&hist[(uint32_t)((i >> 12) << 12) | code], 1);
    cnt[i] = 0;
}

__global__ __launch_bounds__(512) void scan_kernel16(int* __restrict__ hist) {
    __shared__ int lds[512];
    const int t = threadIdx.x;
    int* h = hist + (blockIdx.x << 12);
    const int base = t * 8;
    int v[8];
    int s = 0;
#pragma unroll
    for (int j = 0; j < 8; j++) { v[j] = h[base + j]; s += v[j]; }
    lds[t] = s;
    __syncthreads();
    for (int off = 1; off < 512; off <<= 1) {
        int u = (t >= off) ? lds[t - off] : 0;
        __syncthreads();
        lds[t] += u;
        __syncthreads();
    }
    int run = lds[t] - s;  // exclusive
#pragma unroll
    for (int j = 0; j < 8; j++) { h[base + j] = run; run += v[j]; }
}

__global__ __launch_bounds__(256) void scatter_kernel(const float* __restrict__ pos,
                                                      int* __restrict__ offs,
                                                      float* __restrict__ pp4sf,
                                                      uint16_t* __restrict__ oidx) {
    const int i = blockIdx.x * 256 + threadIdx.x;
    const float* s = pos + (size_t)i * 3;
    float x = s[0], y = s[1], z = s[2];
    float q = __fadd_rn(__fadd_rn(__fmul_rn(x, x), __fmul_rn(y, y)),
                        __fmul_rn(z, z));
    uint32_t code = cellcode(x, y, z);
    int sl = atomicAdd(&offs[(uint32_t)((i >> 12) << 12) | code], 1);
    int gs = ((i >> 12) << 12) | sl;  // global sorted slot
    // pair-packed: floats at 8p: [x0,x1,y0,y1,z0,z1,q0,q1]
    float* dst = pp4sf + (size_t)(gs >> 1) * 8 + (gs & 1);
    dst[0] = x; dst[2] = y; dst[4] = z; dst[6] = q;
    oidx[gs] = (uint16_t)(i & 4095);
}

__global__ __launch_bounds__(256) void bbox_kernel(const float4* __restrict__ pp4s,
                                                   float* __restrict__ bbx) {
    const int grp = blockIdx.x * 8 + (threadIdx.x >> 5);
    const int sub = threadIdx.x & 31;
    const int gs = grp * GSZ + sub;
    float4 A = pp4s[(gs >> 1) * 2 + 0];
    float4 B = pp4s[(gs >> 1) * 2 + 1];
    bool hi = gs & 1;
    float x = hi ? A.y : A.x, y = hi ? A.w : A.z, z = hi ? B.y : B.x;
    float nx = x, xx = x, ny = y, xy = y, nz = z, xz = z;
#pragma unroll
    for (int o = 1; o < 32; o <<= 1) {
        nx = fminf(nx, __shfl_xor(nx, o, 32)); xx = fmaxf(xx, __shfl_xor(xx, o, 32));
        ny = fminf(ny, __shfl_xor(ny, o, 32)); xy = fmaxf(xy, __shfl_xor(xy, o, 32));
        nz = fminf(nz, __shfl_xor(nz, o, 32)); xz = fmaxf(xz, __shfl_xor(xz, o, 32));
    }
    if (sub == 0) {
        float* d = bbx + (size_t)grp * 8;
        d[0] = nx; d[1] = xx; d[2] = ny; d[3] = xy; d[4] = nz; d[5] = xz;
        d[6] = 0.f; d[7] = 0.f;
    }
}

// ---------------------------------------------------------------------------
// SORTED kNN — R4-GREEN STRUCTURE VERBATIM (passed, absmax 0.75) with the
// single QPITCH=198 addressing fix. R5/R6 post-mortem: the sorted-space
// emit + x-permute output rework carries an unlocated defect (R6 restored
// R4's pass1 exactly and still failed ~33 absmax; tau & survivor sets are
// deterministic, so R4's pass was not luck) -> that rework is PARKED.
// Pass1: 32 cross-batch oct-mins/wave (oct j = pairs {w+16j+512m}) -> top-11
// list; tau = 11th-smallest oct-min of the 8-wave union (>=11 distinct cands
// <= tau). Pass2: bbox group-skip + packed replay into per-query LDS list.
// Rescore: 8-way, exact d2, tiebreak by ORIGINAL idx. Merge tree + emit in
// ORIG id space.
// ---------------------------------------------------------------------------
__global__ __launch_bounds__(512, 8) void knn_sorted_kernel(
        const float4* __restrict__ pp4,
        const uint16_t* __restrict__ oidx,
        const float* __restrict__ bbx,
        int* __restrict__ cnt,
        int* __restrict__ colfix,
        int* __restrict__ nbr) {
    // 25.6 KB region, time-multiplexed:
    //   phase A: pass1 lists   512*11 f32    = 22.5 KB
    //   phase B: survivor pool 64 lists, pitch 198 u16 = 25.3 KB
    //   phase C: merge slots   4*64*11 u64   = 22.5 KB
    __shared__ uint64_t smem8[3200];
    __shared__ float tau_s[QG];
    __shared__ uint32_t qcnt[QG];
    float* listf = (float*)smem8;
    uint16_t* pool16 = (uint16_t*)smem8;
    uint64_t* slot = smem8;

    const int tid = threadIdx.x;
    const int lane = tid & 63;
    const int w = __builtin_amdgcn_readfirstlane(tid >> 6);
    const int batch = blockIdx.x & 15;                  // XCD-affinity swizzle
    const int qs = ((blockIdx.x >> 4) << 6) | lane;     // SORTED batch-local query
    const int gbase = batch << 12;
    const int gqs = gbase + qs;

    float4 mA = pp4[(gqs >> 1) * 2 + 0];
    float4 mB = pp4[(gqs >> 1) * 2 + 1];
    const bool hi = (qs & 1);
    const float mx = hi ? mA.y : mA.x;
    const float my = hi ? mA.w : mA.z;
    const float mz = hi ? mB.y : mB.x;
    const float sqi = hi ? mB.w : mB.z;
    const f2 vx22 = {__fmul_rn(-2.0f, mx), __fmul_rn(-2.0f, mx)};
    const f2 vy22 = {__fmul_rn(-2.0f, my), __fmul_rn(-2.0f, my)};
    const f2 vz22 = {__fmul_rn(-2.0f, mz), __fmul_rn(-2.0f, mz)};

    const f2* __restrict__ bp2 = (const f2*)(pp4 + (size_t)gbase);   // batch base
    const f2* __restrict__ cp2 = (const f2*)(pp4 + (size_t)(gbase + w * CH));

#define D8P(cb2)                                                      \
    f2 X0 = (cb2)[0],  Y0 = (cb2)[1],  Z0 = (cb2)[2],  Q0 = (cb2)[3]; \
    f2 X1 = (cb2)[4],  Y1 = (cb2)[5],  Z1 = (cb2)[6],  Q1 = (cb2)[7]; \
    f2 X2 = (cb2)[8],  Y2 = (cb2)[9],  Z2 = (cb2)[10], Q2 = (cb2)[11];\
    f2 X3 = (cb2)[12], Y3 = (cb2)[13], Z3 = (cb2)[14], Q3 = (cb2)[15];\
    f2 e0 = FdP3(X0, Y0, Z0, Q0, vx22, vy22, vz22);                   \
    f2 e1 = FdP3(X1, Y1, Z1, Q1, vx22, vy22, vz22);                   \
    f2 e2 = FdP3(X2, Y2, Z2, Q2, vx22, vy22, vz22);                   \
    f2 e3 = FdP3(X3, Y3, Z3, Q3, vx22, vy22, vz22);

    // ---- pass 1: 32 CROSS-BATCH oct-mins per wave -> top-11 list.
    // Oct j = pairs {w + 16j + 512m : m=0..3} (4 pairs, 512 pairs apart).
    float L[NL2];
#pragma unroll
    for (int t = 0; t < NL2; t++) L[t] = INFF;

#pragma unroll 2
    for (int j = 0; j < 32; ++j) {
        float m = INFF;
#pragma unroll
        for (int s = 0; s < 4; ++s) {
            const f2* c2 = bp2 + (((s << 9) | (j << 4) | w) << 2);  // pair idx *4
            f2 X = c2[0], Y = c2[1], Z = c2[2], Q = c2[3];
            f2 e = FdP3(X, Y, Z, Q, vx22, vy22, vz22);
            m = fminf(m, fminf(e.x, e.y));
        }
        // sorted-descending insert (L[NL2-1] = smallest)
#pragma unroll
        for (int t = 0; t < NL2 - 1; ++t) L[t] = __builtin_amdgcn_fmed3f(L[t], L[t + 1], m);
        L[NL2 - 1] = fminf(L[NL2 - 1], m);
    }
#pragma unroll
    for (int t = 0; t < NL2; t++) listf[tid * LP2 + t] = L[t];
    __syncthreads();

    // ---- merge: 11th-smallest oct-min of the 8-list union -> tau
    if (tid < QG) {
        int p[NW];
#pragma unroll
        for (int u = 0; u < NW; u++) p[u] = NL2 - 1;  // descending; tail = min
        float tau = INFF;
        for (int it = 0; it < NSEL; ++it) {
            float best = INFF;
            int bw = 0;
#pragma unroll
            for (int u = 0; u < NW; u++) {
                float v = (p[u] >= 0) ? listf[((u << 6) | tid) * LP2 + p[u]] : INFF;
                if (v < best) { best = v; bw = u; }
            }
            p[bw]--;
            tau = best;
        }
        tau_s[tid] = tau;
        qcnt[tid] = 0;
    }
    __syncthreads();  // merge reads done; pool16 may now overwrite list region

    // ---- pass 2: bbox group-skip + packed replay into per-query list
    const float t0v = tau_s[lane];
    const float tau = t0v + fabsf(t0v) * 1e-4f + 1e-4f;
    const float taud2 = __fadd_rn(tau, sqi) + 1e-4f;  // true-d2-space bound
#pragma unroll 1
    for (int og = 0; og < 16; ++og) {
        const float* bb = bbx + (size_t)((batch << 7) | (w << 4) | og) * 8;
        float dx = fmaxf(fmaxf(bb[0] - mx, mx - bb[1]), 0.0f);
        float dy = fmaxf(fmaxf(bb[2] - my, my - bb[3]), 0.0f);
        float dz = fmaxf(fmaxf(bb[4] - mz, mz - bb[5]), 0.0f);
        float d2lb = dx * dx + dy * dy + dz * dz;
        if (__any(d2lb <= taud2)) {
#pragma unroll
            for (int s = 0; s < 4; ++s) {
                const f2* cb2 = cp2 + (og * 4 + s) * 16;
                D8P(cb2);
                const uint32_t jb = (uint32_t)(w * CH + (og * 4 + s) * 8);
                bool h0 = e0.x <= tau, h1 = e0.y <= tau, h2 = e1.x <= tau, h3 = e1.y <= tau;
                bool h4 = e2.x <= tau, h5 = e2.y <= tau, h6 = e3.x <= tau, h7 = e3.y <= tau;
#define PUSH(hv, off)                                                   \
                if (hv) {                                               \
                    uint32_t p = atomicAdd(&qcnt[lane], 1u);            \
                    if (p < QCAP) pool16[lane * QPITCH + p] = (uint16_t)(jb + (off)); \
                }
                if (h0 | h1) { PUSH(h0, 0) PUSH(h1, 1) }
                if (h2 | h3) { PUSH(h2, 2) PUSH(h3, 3) }
                if (h4 | h5) { PUSH(h4, 4) PUSH(h5, 5) }
                if (h6 | h7) { PUSH(h6, 6) PUSH(h7, 7) }
#undef PUSH
            }
        }
    }
    __syncthreads();  // all pushes visible (lists are cross-wave now)

    // ---- rescore: wave w takes entries w, w+8, ... of its lane-query's list.
    // Key = (d2exact << 32) | ORIGINAL idx -> tie order matches reference.
    uint64_t S[KK];
#pragma unroll
    for (int t = 0; t < KK; t++) S[t] = ~0ull;
    {
        uint32_t len = qcnt[lane];
        if (len > QCAP) len = QCAP;
        const uint16_t* st = pool16 + lane * QPITCH;
        for (uint32_t e = (uint32_t)w; e < len; e += NW) {
            uint32_t ix = st[e];
            if (ix == (uint32_t)qs) continue;  // self (sorted id)
            int g = gbase + (int)ix;
            float4 A4 = pp4[(g >> 1) * 2 + 0];
            float4 B4 = pp4[(g >> 1) * 2 + 1];
            bool ch = (ix & 1);
            uint32_t db = d2exact(mx, my, mz, sqi,
                                  ch ? A4.y : A4.x, ch ? A4.w : A4.z,
                                  ch ? B4.y : B4.x, ch ? B4.w : B4.z);
            uint32_t orig = (uint32_t)oidx[g];
            uint64_t k64 = ((uint64_t)db << 32) | orig;
            if (k64 < S[0]) {
                bool sh[KK];
                sh[0] = true;
#pragma unroll
                for (int t = 1; t < KK; t++) sh[t] = (k64 < S[t]);
#pragma unroll
                for (int t = 0; t < KK; t++) {
                    uint64_t vac = sh[t] ? k64 : S[t];
                    S[t] = (t + 1 < KK) ? (sh[t + 1] ? S[t + 1] : vac) : vac;
                }
            }
        }
    }
    __syncthreads();  // all pool reads done; slots may overwrite pool region

    // ---- merge tree: rank-scatter ('<' A side, '<=' B side -> bijective)
    if (w >= 4) {
        uint64_t* sl = slot + (((w - 4) << 6) | lane) * SLOTP;
#pragma unroll
        for (int j = 0; j < KK; ++j) sl[j] = S[KK - 1 - j];  // ascending
    }
    __syncthreads();

    if (w < 4) {
        uint64_t* sl = slot + ((w << 6) | lane) * SLOTP;
        uint64_t P[KK];
#pragma unroll
        for (int j = 0; j < KK; ++j) P[j] = sl[j];
#pragma unroll
        for (int j = 0; j < KK; ++j) {
            uint64_t v = S[KK - 1 - j];
            uint32_t r = (uint32_t)j;
#pragma unroll
            for (int i = 0; i < KK; ++i) r += (P[i] < v) ? 1u : 0u;
            if (r < KK) sl[r] = v;
        }
#pragma unroll
        for (int i = 0; i < KK; ++i) {
            uint64_t v = P[i];
            uint32_t r = (uint32_t)i;
#pragma unroll
            for (int t = 0; t < KK; ++t) r += (S[t] <= v) ? 1u : 0u;
            if (r < KK) sl[r] = v;
        }
    }
    __syncthreads();

    if (w < 2) {
        uint64_t* sa = slot + (((w * 2) << 6) | lane) * SLOTP;
        uint64_t* sb = slot + (((w * 2 + 1) << 6) | lane) * SLOTP;
        uint64_t Aa[KK], Bb[KK];
#pragma unroll
        for (int j = 0; j < KK; ++j) Aa[j] = sa[j];
#pragma unroll
        for (int j = 0; j < KK; ++j) Bb[j] = sb[j];
#pragma unroll
        for (int j = 0; j < KK; ++j) {
            uint32_t r = (uint32_t)j;
#pragma unroll
            for (int i = 0; i < KK; ++i) r += (Bb[i] < Aa[j]) ? 1u : 0u;
            if (r < KK) sa[r] = Aa[j];
        }
#pragma unroll
        for (int i = 0; i < KK; ++i) {
            uint32_t r = (uint32_t)i;
#pragma unroll
            for (int j = 0; j < KK; ++j) r += (Aa[j] <= Bb[i]) ? 1u : 0u;
            if (r < KK) sa[r] = Bb[i];
        }
    }
    __syncthreads();

    if (tid < QG) {
        const uint64_t* sa = slot + ((0 << 6) | tid) * SLOTP;
        const uint64_t* sb = slot + ((2 << 6) | tid) * SLOTP;
        uint64_t Aa[KK], Bb[KK];
#pragma unroll
        for (int j = 0; j < KK; ++j) Aa[j] = sa[j];
#pragma unroll
        for (int j = 0; j < KK; ++j) Bb[j] = sb[j];
        const int gq_o = gbase + (int)oidx[gbase + qs];  // orig query id
        // sentinel guard: with valid tau this never triggers; it prevents
        // memory corruption if an assumption ever breaks.
#define EMIT(key, rk)                                              \
        if ((uint32_t)((key) >> 32) != 0xffffffffu) {              \
            int jl = (int)((key) & 0xffffffffu);                   \
            int gj = gbase + jl;   /* key already holds ORIG idx */\
            int p = atomicAdd(&cnt[gj], 1);                        \
            if (colfix) {                                          \
                if (p < 64) colfix[(gj << 6) | p] = gq_o;          \
            } else {                                               \
                nbr[gq_o * KK + (int)(rk)] = gj;                   \
            }                                                      \
        }
#pragma unroll
        for (int j = 0; j < KK; ++j) {
            uint32_t r = (uint32_t)j;
#pragma unroll
            for (int i = 0; i < KK; ++i) r += (Bb[i] < Aa[j]) ? 1u : 0u;
            if (r < KK) EMIT(Aa[j], r)
        }
#pragma unroll
        for (int i = 0; i < KK; ++i) {
            uint32_t r = (uint32_t)i;
#pragma unroll
            for (int j = 0; j < KK; ++j) r += (Aa[j] <= Bb[i]) ? 1u : 0u;
            if (r < KK) EMIT(Bb[i], r)
        }
#undef EMIT
    }
#undef D8P
}

// ---------------------------------------------------------------------------
// UNSORTED prep + kNN (round-1 verbatim) - fallback when ws lacks sort space.
// ---------------------------------------------------------------------------
__global__ __launch_bounds__(256) void prep_kernel(const float* __restrict__ pos,
                                                   float4* __restrict__ pp4,
                                                   int* __restrict__ cnt) {
    const int p = blockIdx.x * 256 + threadIdx.x;
    const float* s = pos + (size_t)p * 6;
    float x0 = s[0], y0 = s[1], z0 = s[2];
    float x1 = s[3], y1 = s[4], z1 = s[5];
    float q0 = __fadd_rn(__fadd_rn(__fmul_rn(x0, x0), __fmul_rn(y0, y0)),
                         __fmul_rn(z0, z0));
    float q1 = __fadd_rn(__fadd_rn(__fmul_rn(x1, x1), __fmul_rn(y1, y1)),
                         __fmul_rn(z1, z1));
    pp4[2 * p + 0] = make_float4(x0, x1, y0, y1);
    pp4[2 * p + 1] = make_float4(z0, z1, q0, q1);
    cnt[2 * p + 0] = 0;
    cnt[2 * p + 1] = 0;
}

__global__ __launch_bounds__(512, 8) void knn_kernel(const float4* __restrict__ pp4,
                                                     int* __restrict__ cnt,
                                                     int* __restrict__ colfix,
                                                     int* __restrict__ nbr) {
    __shared__ uint64_t smem8[3200];
    __shared__ float tau_s[QG];
    float* listf = (float*)smem8;
    uint16_t* pool16 = (uint16_t*)smem8;
    uint64_t* slot = smem8;

    const int tid = threadIdx.x;
    const int lane = tid & 63;
    const int w = __builtin_amdgcn_readfirstlane(tid >> 6);
    const int batch = blockIdx.x & 15;
    const int qloc = ((blockIdx.x >> 4) << 6) | lane;
    const int gbase = batch << 12;
    const int gq = gbase + qloc;

    float4 mA = pp4[(gq >> 1) * 2 + 0];
    float4 mB = pp4[(gq >> 1) * 2 + 1];
    const bool hi = (qloc & 1);
    const float mx = hi ? mA.y : mA.x;
    const float my = hi ? mA.w : mA.z;
    const float mz = hi ? mB.y : mB.x;
    const float sqi = hi ? mB.w : mB.z;
    const f2 vx22 = {__fmul_rn(-2.0f, mx), __fmul_rn(-2.0f, mx)};
    const f2 vy22 = {__fmul_rn(-2.0f, my), __fmul_rn(-2.0f, my)};
    const f2 vz22 = {__fmul_rn(-2.0f, mz), __fmul_rn(-2.0f, mz)};

    const f2* __restrict__ cp2 = (const f2*)(pp4 + (size_t)(gbase + w * CH));

#define D8P(cb2)                                                      \
    f2 X0 = (cb2)[0],  Y0 = (cb2)[1],  Z0 = (cb2)[2],  Q0 = (cb2)[3]; \
    f2 X1 = (cb2)[4],  Y1 = (cb2)[5],  Z1 = (cb2)[6],  Q1 = (cb2)[7]; \
    f2 X2 = (cb2)[8],  Y2 = (cb2)[9],  Z2 = (cb2)[10], Q2 = (cb2)[11];\
    f2 X3 = (cb2)[12], Y3 = (cb2)[13], Z3 = (cb2)[14], Q3 = (cb2)[15];\
    f2 e0 = FdP3(X0, Y0, Z0, Q0, vx22, vy22, vz22);                   \
    f2 e1 = FdP3(X1, Y1, Z1, Q1, vx22, vy22, vz22);                   \
    f2 e2 = FdP3(X2, Y2, Z2, Q2, vx22, vy22, vz22);                   \
    f2 e3 = FdP3(X3, Y3, Z3, Q3, vx22, vy22, vz22);

    float L[NL];
#pragma unroll
    for (int t = 0; t < NL; t++) L[t] = INFF;

#pragma unroll 2
    for (int g = 0; g < NL; ++g) {
        float gm = INFF;
#pragma unroll
        for (int s = 0; s < 4; ++s) {
            const f2* cb2 = cp2 + (g * 4 + s) * 16;
            D8P(cb2);
            float m = fminf(fminf(fminf(e0.x, e0.y), fminf(e1.x, e1.y)),
                            fminf(fminf(e2.x, e2.y), fminf(e3.x, e3.y)));
            gm = fminf(gm, m);
        }
#pragma unroll
        for (int t = 0; t < NL - 1; ++t) L[t] = __builtin_amdgcn_fmed3f(L[t], L[t + 1], gm);
        L[NL - 1] = fminf(L[NL - 1], gm);
    }
#pragma unroll
    for (int t = 0; t < NL; t++) listf[tid * LPITCH + t] = L[t];
    __syncthreads();

    if (tid < QG) {
        int p[NW];
#pragma unroll
        for (int u = 0; u < NW; u++) p[u] = NL - 1;
        float tau = INFF;
        for (int it = 0; it < NSEL; ++it) {
            float best = INFF;
            int bw = 0;
#pragma unroll
            for (int u = 0; u < NW; u++) {
                float v = (p[u] >= 0) ? listf[((u << 6) | tid) * LPITCH + p[u]] : INFF;
                if (v < best) { best = v; bw = u; }
            }
            p[bw]--;
            tau = best;
        }
        tau_s[tid] = tau;
    }
    __syncthreads();

    const float t0v = tau_s[lane];
    const float tau = t0v + fabsf(t0v) * 1e-4f + 1e-4f;
    const uint32_t cell0 = (uint32_t)(((w << 6) | lane) * WPITCH);
    uint32_t cpos = cell0;
#pragma unroll 2
    for (int o = 0; o < CH / 8; ++o) {
        const f2* cb2 = cp2 + o * 16;
        D8P(cb2);
        const uint32_t jb = (uint32_t)(w * CH + o * 8);
        bool h0 = e0.x <= tau, h1 = e0.y <= tau, h2 = e1.x <= tau, h3 = e1.y <= tau;
        bool h4 = e2.x <= tau, h5 = e2.y <= tau, h6 = e3.x <= tau, h7 = e3.y <= tau;
#define PUSH(hv, off)                                              \
        if ((hv) && cpos < cell0 + WCAP) {                         \
            pool16[cpos] = (uint16_t)(jb + (off));                 \
            cpos++;                                                \
        }
        if (h0 | h1) { PUSH(h0, 0) PUSH(h1, 1) }
        if (h2 | h3) { PUSH(h2, 2) PUSH(h3, 3) }
        if (h4 | h5) { PUSH(h4, 4) PUSH(h5, 5) }
        if (h6 | h7) { PUSH(h6, 6) PUSH(h7, 7) }
#undef PUSH
    }

    uint64_t S[KK];
#pragma unroll
    for (int t = 0; t < KK; t++) S[t] = ~0ull;
    {
        const uint16_t* st = pool16 + cell0;
        const int c2i = (int)(cpos - cell0);
        for (int e = 0; e < c2i; ++e) {
            uint32_t ix = st[e];
            if (ix == (uint32_t)qloc) continue;
            int g = gbase + (int)ix;
            float4 A4 = pp4[(g >> 1) * 2 + 0];
            float4 B4 = pp4[(g >> 1) * 2 + 1];
            bool ch = (ix & 1);
            uint32_t db = d2exact(mx, my, mz, sqi,
                                  ch ? A4.y : A4.x, ch ? A4.w : A4.z,
                                  ch ? B4.y : B4.x, ch ? B4.w : B4.z);
            uint64_t k64 = ((uint64_t)db << 32) | ix;
            if (k64 < S[0]) {
                bool sh[KK];
                sh[0] = true;
#pragma unroll
                for (int t = 1; t < KK; t++) sh[t] = (k64 < S[t]);
#pragma unroll
                for (int t = 0; t < KK; t++) {
                    uint64_t vac = sh[t] ? k64 : S[t];
                    S[t] = (t + 1 < KK) ? (sh[t + 1] ? S[t + 1] : vac) : vac;
                }
            }
        }
    }
    __syncthreads();

    if (w >= 4) {
        uint64_t* sl = slot + (((w - 4) << 6) | lane) * SLOTP;
#pragma unroll
        for (int j = 0; j < KK; ++j) sl[j] = S[KK - 1 - j];
    }
    __syncthreads();

    if (w < 4) {
        uint64_t* sl = slot + ((w << 6) | lane) * SLOTP;
        uint64_t P[KK];
#pragma unroll
        for (int j = 0; j < KK; ++j) P[j] = sl[j];
#pragma unroll
        for (int j = 0; j < KK; ++j) {
            uint64_t v = S[KK - 1 - j];
            uint32_t r = (uint32_t)j;
#pragma unroll
            for (int i = 0; i < KK; ++i) r += (P[i] < v) ? 1u : 0u;
            if (r < KK) sl[r] = v;
        }
#pragma unroll
        for (int i = 0; i < KK; ++i) {
            uint64_t v = P[i];
            uint32_t r = (uint32_t)i;
#pragma unroll
            for (int t = 0; t < KK; ++t) r += (S[t] <= v) ? 1u : 0u;
            if (r < KK) sl[r] = v;
        }
    }
    __syncthreads();

    if (w < 2) {
        uint64_t* sa = slot + (((w * 2) << 6) | lane) * SLOTP;
        uint64_t* sb = slot + (((w * 2 + 1) << 6) | lane) * SLOTP;
        uint64_t Aa[KK], Bb[KK];
#pragma unroll
        for (int j = 0; j < KK; ++j) Aa[j] = sa[j];
#pragma unroll
        for (int j = 0; j < KK; ++j) Bb[j] = sb[j];
#pragma unroll
        for (int j = 0; j < KK; ++j) {
            uint32_t r = (uint32_t)j;
#pragma unroll
            for (int i = 0; i < KK; ++i) r += (Bb[i] < Aa[j]) ? 1u : 0u;
            if (r < KK) sa[r] = Aa[j];
        }
#pragma unroll
        for (int i = 0; i < KK; ++i) {
            uint32_t r = (uint32_t)i;
#pragma unroll
            for (int j = 0; j < KK; ++j) r += (Aa[j] <= Bb[i]) ? 1u : 0u;
            if (r < KK) sa[r] = Bb[i];
        }
    }
    __syncthreads();

    if (tid < QG) {
        const uint64_t* sa = slot + ((0 << 6) | tid) * SLOTP;
        const uint64_t* sb = slot + ((2 << 6) | tid) * SLOTP;
        uint64_t Aa[KK], Bb[KK];
#pragma unroll
        for (int j = 0; j < KK; ++j) Aa[j] = sa[j];
#pragma unroll
        for (int j = 0; j < KK; ++j) Bb[j] = sb[j];
#define EMIT(key, rk)                                              \
        {                                                          \
            int jl = (int)((key) & 0xffffffffu);                   \
            int gj = gbase + jl;                                   \
            int p = atomicAdd(&cnt[gj], 1);                        \
            if (colfix) {                                          \
                if (p < 64) colfix[(gj << 6) | p] = gq;            \
            } else {                                               \
                nbr[gq * KK + (int)(rk)] = gj;                     \
            }                                                      \
        }
#pragma unroll
        for (int j = 0; j < KK; ++j) {
            uint32_t r = (uint32_t)j;
#pragma unroll
            for (int i = 0; i < KK; ++i) r += (Bb[i] < Aa[j]) ? 1u : 0u;
            if (r < KK) EMIT(Aa[j], r)
        }
#pragma unroll
        for (int i = 0; i < KK; ++i) {
            uint32_t r = (uint32_t)i;
#pragma unroll
            for (int j = 0; j < KK; ++j) r += (Aa[j] <= Bb[i]) ? 1u : 0u;
            if (r < KK) EMIT(Bb[i], r)
        }
#undef EMIT
    }
#undef D8P
}

// ---------------------------------------------------------------------------
// Bucket-path output (orig id space — R0-proven).
// ---------------------------------------------------------------------------
__global__ __launch_bounds__(256) void out_bucket_kernel(const float4* __restrict__ x4,
                                                         const int* __restrict__ colfix,
                                                         const int* __restrict__ cnt,
                                                         float* __restrict__ out) {
    const int b = blockIdx.x;
    const int g = b & 15;
    const int i = b >> 4;
    const int l = threadIdx.x & 31;
    const int n = (g << 12) | (i << 3) | (threadIdx.x >> 5);
    const int s = l & 15;
    const int half = l >> 4;
    const int c = cnt[n];
    const int cc = (c > 64) ? 64 : c;
    const int4* cf4 = (const int4*)(colfix + ((size_t)n << 6));
    float4 acc = make_float4(0.f, 0.f, 0.f, 0.f);
    for (int eb = half * 4; eb < cc; eb += 8) {
        int4 Q = cf4[eb >> 2];
        float4 v0 = x4[((size_t)Q.x << 4) | s];
        acc.x += v0.x; acc.y += v0.y; acc.z += v0.z; acc.w += v0.w;
        if (eb + 1 < cc) {
            float4 v1 = x4[((size_t)Q.y << 4) | s];
            acc.x += v1.x; acc.y += v1.y; acc.z += v1.z; acc.w += v1.w;
        }
        if (eb + 2 < cc) {
            float4 v2 = x4[((size_t)Q.z << 4) | s];
            acc.x += v2.x; acc.y += v2.y; acc.z += v2.z; acc.w += v2.w;
        }
        if (eb + 3 < cc) {
            float4 v3 = x4[((size_t)Q.w << 4) | s];
            acc.x += v3.x; acc.y += v3.y; acc.z += v3.z; acc.w += v3.w;
        }
    }
    acc.x += __shfl_xor(acc.x, 16, 64);
    acc.y += __shfl_xor(acc.y, 16, 64);
    acc.z += __shfl_xor(acc.z, 16, 64);
    acc.w += __shfl_xor(acc.w, 16, 64);
    const float inv = 1.0f / (float)(c > 1 ? c : 1);
    float4 mn = x4[((size_t)n << 4) | s];
    float v = fabsf(mn.x - acc.x * inv) + fabsf(mn.y - acc.y * inv) +
              fabsf(mn.z - acc.z * inv) + fabsf(mn.w - acc.w * inv);
    v += __shfl_xor(v, 1, 64);
    v += __shfl_xor(v, 2, 64);
    v += __shfl_xor(v, 4, 64);
    v += __shfl_xor(v, 8, 64);
    if (l == 0) out[n] = v;
}

// ------------------------- fallback path (small ws) -------------------------
__global__ __launch_bounds__(1024) void scan_kernel(const int* __restrict__ cnt,
                                                    int* __restrict__ offs) {
    __shared__ int lds[1024];
    const int t = threadIdx.x;
    const int base = t * 64;
    int s = 0;
    for (int i = 0; i < 64; i++) s += cnt[base + i];
    lds[t] = s;
    __syncthreads();
    for (int off = 1; off < 1024; off <<= 1) {
        int v = (t >= off) ? lds[t - off] : 0;
        __syncthreads();
        lds[t] += v;
        __syncthreads();
    }
    int run = lds[t] - s;
    for (int i = 0; i < 64; i++) {
        offs[base + i] = run;
        run += cnt[base + i];
    }
}

__global__ __launch_bounds__(256) void fill_kernel(const int* __restrict__ nbr,
                                                   int* __restrict__ offs,
                                                   int* __restrict__ col) {
    const int i = blockIdx.x * 256 + threadIdx.x;
#pragma unroll
    for (int t = 0; t < KK; t++) {
        int j = nbr[i * KK + t];
        int p = atomicAdd(&offs[j], 1);
        col[p] = i;
    }
}

__global__ __launch_bounds__(256) void out_kernel(const float* __restrict__ x,
                                                  const int* __restrict__ col,
                                                  const int* __restrict__ offs_end,
                                                  const int* __restrict__ cnt,
                                                  float* __restrict__ out) {
    const int gtid = blockIdx.x * 256 + threadIdx.x;
    const int n = gtid >> 6;
    const int lane = gtid & 63;
    const int c = cnt[n];
    const int end = offs_end[n];
    const int start = end - c;
    float s = 0.0f;
    for (int e = start; e < end; e++) {
        int i = col[e];
        s += x[(size_t)i * FD + lane];
    }
    float mean = s / (float)(c > 1 ? c : 1);
    float v = fabsf(x[(size_t)n * FD + lane] - mean);
#pragma unroll
    for (int off = 32; off; off >>= 1) v += __shfl_xor(v, off, 64);
    if (lane == 0) out[n] = v;
}

extern "C" void kernel_launch(void* const* d_in, const int* in_sizes, int n_in,
                              void* d_out, int out_size, void* d_ws, size_t ws_size,
                              hipStream_t stream) {
    const float* x = (const float*)d_in[0];
    const float* pos = (const float*)d_in[1];
    float* out = (float*)d_out;

    char* ws = (char*)d_ws;
    float4* pp4 = (float4*)(ws + 0);            // 1,048,576 B (sorted or unsorted)
    int* cnt = (int*)(ws + 1048576);            //   262,144 B
    int* colfix = (int*)(ws + 1310720);         // 16,777,216 B (bucket path)
    int* nbr = (int*)(ws + 1310720);            //  2,621,440 B (fallback path)
    int* offs = (int*)(ws + 3932160);
    int* col = (int*)(ws + 4194304);
    // sorted-path extras (past colfix):
    int* hist = (int*)(ws + OFF_HIST);          //   262,144 B (bins, then offsets)
    uint16_t* oidx = (uint16_t*)(ws + OFF_OIDX);//   131,072 B (sorted -> orig)
    float* bbx = (float*)(ws + OFF_BBX);        //    65,536 B (group bboxes)

    const bool bucket = ws_size >= (size_t)(1310720 + TOTAL * 64 * 4);
    const bool sorted = ws_size >= (size_t)SORTED_NEED;  // implies bucket

    if (sorted) {
        hipMemsetAsync(hist, 0, NB * 4096 * sizeof(int), stream);
        hipLaunchKernelGGL(hist_kernel, dim3(TOTAL / 256), dim3(256), 0, stream,
                           pos, hist, cnt);
        hipLaunchKernelGGL(scan_kernel16, dim3(NB), dim3(512), 0, stream, hist);
        hipLaunchKernelGGL(scatter_kernel, dim3(TOTAL / 256), dim3(256), 0, stream,
                           pos, hist, (float*)pp4, oidx);
        hipLaunchKernelGGL(bbox_kernel, dim3(NGRP / 8), dim3(256), 0, stream,
                           pp4, bbx);
        hipLaunchKernelGGL(knn_sorted_kernel, dim3(TOTAL / QG), dim3(512), 0, stream,
                           pp4, oidx, bbx, cnt, colfix, (int*)nullptr);
        hipLaunchKernelGGL(out_bucket_kernel, dim3(TOTAL * 32 / 256), dim3(256), 0, stream,
                           (const float4*)x, colfix, cnt, out);
    } else {
        hipLaunchKernelGGL(prep_kernel, dim3(TOTAL / 2 / 256), dim3(256), 0, stream,
                           pos, pp4, cnt);
        hipLaunchKernelGGL(knn_kernel, dim3(TOTAL / QG), dim3(512), 0, stream, pp4, cnt,
                           bucket ? colfix : (int*)nullptr, bucket ? (int*)nullptr : nbr);
        if (bucket) {
            hipLaunchKernelGGL(out_bucket_kernel, dim3(TOTAL * 32 / 256), dim3(256), 0, stream,
                               (const float4*)x, colfix, cnt, out);
        } else {
            hipLaunchKernelGGL(scan_kernel, dim3(1), dim3(1024), 0, stream, cnt, offs);
            hipLaunchKernelGGL(fill_kernel, dim3(TOTAL / 256), dim3(256), 0, stream, nbr, offs, col);
            hipLaunchKernelGGL(out_kernel, dim3(TOTAL * FD / 256), dim3(256), 0, stream,
                               x, col, offs, cnt, out);
        }
    }
}